// Round 14
// baseline (224.497 us; speedup 1.0000x reference)
//
#include <hip/hip_runtime.h>
#include <hip/hip_bf16.h>

// CrissCrossAttention (full spatial attention with w<->k permuted PV):
//   B=4, C=512, H=W=64, C8=64, HW=4096.
// v8: FUSED attention kernel k_att = QK^T + softmax(v) + PV + epilogue.
//   No P intermediate in HBM (was 128MB write + 100MB read + a whole kernel).
//   k_wcat  : pack [wq;wk;wv] -> Wcat bf16 [640][512]
//   k_prep  : x fp32 -> xT bf16 [B][pixel][512]
//   k_projqk: GEMM rows 0..127 of Wcat -> qfT/kfT bf16 [B][pixel][64]
//   k_projv : GEMM rows 128..639, n-tile = permuted pixels -> Vp2[c][k*64+h]
//   k_att   : per block (c0,w-pair,b): loop s=k: stage K-tile 8KB; QK^T (Q-frags
//             hoisted to regs); softmax over v (sum-only, no max-sub -- |e|~N(0,1.6^2));
//             P-tile -> LDS (v7 B-layout/swizzle); PV from LDS (v7 pattern);
//             gamma*out + x epilogue. A (Vp2) XOR-swizzled gload_lds dbuf.
//             LDS 80KB: A[0,32K) dbuf | K[32K,48K) dbuf | Q[48K,64K) | P[64K,80K).

typedef __bf16 bf16_t;
typedef __bf16 bf16x8 __attribute__((ext_vector_type(8)));
typedef __bf16 bf16x4 __attribute__((ext_vector_type(4)));
typedef float f32x4 __attribute__((ext_vector_type(4)));

#define HW_ 4096
#define CIN 512
#define CQ 64

__device__ __forceinline__ void gload16(const void* g, void* l) {
  __builtin_amdgcn_global_load_lds((const __attribute__((address_space(1))) void*)g,
                                   (__attribute__((address_space(3))) void*)l, 16, 0, 0);
}

// ---------------- weights pack ----------------
__global__ __launch_bounds__(256) void k_wcat(const float* __restrict__ wq,
                                              const float* __restrict__ wk,
                                              const float* __restrict__ wv,
                                              bf16_t* __restrict__ Wcat) {
  int idx = (blockIdx.x * 256 + threadIdx.x) * 4;
  int row = idx >> 9, c = idx & 511;
  const float* src;
  if (row < 64)       src = wq + row * 512 + c;
  else if (row < 128) src = wk + (row - 64) * 512 + c;
  else                src = wv + (row - 128) * 512 + c;
  float4 v = *(const float4*)src;
  bf16x4 o = { (bf16_t)v.x, (bf16_t)v.y, (bf16_t)v.z, (bf16_t)v.w };
  *(bf16x4*)&Wcat[idx] = o;
}

// ---------------- x transpose + bf16 ----------------
__global__ __launch_bounds__(256) void k_prep(const float* __restrict__ x, bf16_t* __restrict__ xT) {
  __shared__ float tile[64][65];
  const int b = blockIdx.z;
  const int p0 = blockIdx.x * 64, c0 = blockIdx.y * 64;
  const float* xb = x + (size_t)b * CIN * HW_;
  bf16_t* xTb = xT + (size_t)b * HW_ * CIN;
  const int tid = threadIdx.x;
  const int r = tid >> 4, q = tid & 15;
#pragma unroll
  for (int i = 0; i < 4; ++i) {
    int lr = r + 16 * i;
    float4 v = *(const float4*)&xb[(size_t)(c0 + lr) * HW_ + p0 + q * 4];
    tile[lr][q * 4 + 0] = v.x; tile[lr][q * 4 + 1] = v.y;
    tile[lr][q * 4 + 2] = v.z; tile[lr][q * 4 + 3] = v.w;
  }
  __syncthreads();
#pragma unroll
  for (int i = 0; i < 4; ++i) {
    int pr = r + 16 * i;
    bf16x4 o;
    o[0] = (bf16_t)tile[q * 4 + 0][pr];
    o[1] = (bf16_t)tile[q * 4 + 1][pr];
    o[2] = (bf16_t)tile[q * 4 + 2][pr];
    o[3] = (bf16_t)tile[q * 4 + 3][pr];
    *(bf16x4*)&xTb[(size_t)(p0 + pr) * CIN + c0 + q * 4] = o;
  }
}

// ---------------- q/k projection GEMM (Wcat rows 0..127) ----------------
__global__ __launch_bounds__(256) void k_projqk(const bf16_t* __restrict__ Wcat,
                                                const bf16_t* __restrict__ xT,
                                                const float* __restrict__ bq,
                                                const float* __restrict__ bk,
                                                bf16_t* __restrict__ qfT,
                                                bf16_t* __restrict__ kfT) {
  __shared__ bf16_t As[128][64];
  __shared__ bf16_t Bs[128][64];
  const int b = blockIdx.z;
  const int n0 = blockIdx.x * 128;
  const char* Wb = (const char*)Wcat;
  const char* Xb = (const char*)(xT + (size_t)b * HW_ * CIN);
  const int tid = threadIdx.x, wv_ = tid >> 6, lane = tid & 63;
  const int wm = wv_ >> 1, wn = wv_ & 1;
  const int g = lane >> 4, cc = lane & 15;
  f32x4 acc[4][4]{};
  for (int ks = 0; ks < 512; ks += 64) {
    if (ks) __syncthreads();
#pragma unroll
    for (int i = 0; i < 4; ++i) {
      int ch = wv_ * 4 + i;
      int rr = ch * 8 + (lane >> 3);
      int sl = (lane & 7) ^ (rr & 7);
      gload16(Wb + (size_t)rr * 1024 + ks * 2 + sl * 16, (char*)As + ch * 1024);
      gload16(Xb + (size_t)(n0 + rr) * 1024 + ks * 2 + sl * 16, (char*)Bs + ch * 1024);
    }
    __syncthreads();
#pragma unroll
    for (int k2 = 0; k2 < 2; ++k2) {
      bf16x8 a[4], bb[4];
#pragma unroll
      for (int f = 0; f < 4; ++f)
        a[f] = *(const bf16x8*)((char*)As + (wm * 64 + f * 16 + cc) * 128 + (((k2 * 4 + g) ^ (cc & 7)) * 16));
#pragma unroll
      for (int f = 0; f < 4; ++f)
        bb[f] = *(const bf16x8*)((char*)Bs + (wn * 64 + f * 16 + cc) * 128 + (((k2 * 4 + g) ^ (cc & 7)) * 16));
#pragma unroll
      for (int fm = 0; fm < 4; ++fm)
#pragma unroll
        for (int fn = 0; fn < 4; ++fn)
          acc[fm][fn] = __builtin_amdgcn_mfma_f32_16x16x32_bf16(a[fm], bb[fn], acc[fm][fn], 0, 0, 0);
    }
  }
  bf16_t* qb = qfT + (size_t)b * HW_ * CQ;
  bf16_t* kb = kfT + (size_t)b * HW_ * CQ;
#pragma unroll
  for (int fm = 0; fm < 4; ++fm) {
#pragma unroll
    for (int j = 0; j < 4; ++j) {
      int m = wm * 64 + fm * 16 + g * 4 + j;
      float bias = (m < 64) ? bq[m] : bk[m - 64];
#pragma unroll
      for (int fn = 0; fn < 4; ++fn) {
        int n = n0 + wn * 64 + fn * 16 + cc;
        float val = acc[fm][fn][j] + bias;
        if (m < 64) qb[(size_t)n * CQ + m] = (bf16_t)val;
        else        kb[(size_t)n * CQ + (m - 64)] = (bf16_t)val;
      }
    }
  }
}

// ---------------- V projection GEMM (Wcat rows 128..639, permuted pixels) ----------------
__global__ __launch_bounds__(256) void k_projv(const bf16_t* __restrict__ Wcat,
                                               const bf16_t* __restrict__ xT,
                                               const float* __restrict__ bv,
                                               bf16_t* __restrict__ Vp2) {
  __shared__ bf16_t As[128][64];
  __shared__ bf16_t Bs[128][64];
  const int b = blockIdx.z;
  const int n0 = blockIdx.x * 128, m0 = blockIdx.y * 128;
  const char* Wb = (const char*)Wcat;
  const char* Xb = (const char*)(xT + (size_t)b * HW_ * CIN);
  const int tid = threadIdx.x, wv_ = tid >> 6, lane = tid & 63;
  const int wm = wv_ >> 1, wn = wv_ & 1;
  const int g = lane >> 4, cc = lane & 15;
  f32x4 acc[4][4]{};
  for (int ks = 0; ks < 512; ks += 64) {
    if (ks) __syncthreads();
#pragma unroll
    for (int i = 0; i < 4; ++i) {
      int ch = wv_ * 4 + i;
      int rr = ch * 8 + (lane >> 3);
      int sl = (lane & 7) ^ (rr & 7);
      int pix = (rr & 63) * 64 + (blockIdx.x * 2) + (rr >> 6);  // perm(n0+rr)
      gload16(Wb + (size_t)(128 + m0 + rr) * 1024 + ks * 2 + sl * 16, (char*)As + ch * 1024);
      gload16(Xb + (size_t)pix * 1024 + ks * 2 + sl * 16, (char*)Bs + ch * 1024);
    }
    __syncthreads();
#pragma unroll
    for (int k2 = 0; k2 < 2; ++k2) {
      bf16x8 a[4], bb[4];
#pragma unroll
      for (int f = 0; f < 4; ++f)
        a[f] = *(const bf16x8*)((char*)As + (wm * 64 + f * 16 + cc) * 128 + (((k2 * 4 + g) ^ (cc & 7)) * 16));
#pragma unroll
      for (int f = 0; f < 4; ++f)
        bb[f] = *(const bf16x8*)((char*)Bs + (wn * 64 + f * 16 + cc) * 128 + (((k2 * 4 + g) ^ (cc & 7)) * 16));
#pragma unroll
      for (int fm = 0; fm < 4; ++fm)
#pragma unroll
        for (int fn = 0; fn < 4; ++fn)
          acc[fm][fn] = __builtin_amdgcn_mfma_f32_16x16x32_bf16(a[fm], bb[fn], acc[fm][fn], 0, 0, 0);
    }
  }
  bf16_t* Vb = Vp2 + (size_t)b * CIN * HW_;
#pragma unroll
  for (int fm = 0; fm < 4; ++fm) {
#pragma unroll
    for (int j = 0; j < 4; ++j) {
      int m = m0 + wm * 64 + fm * 16 + g * 4 + j;
      float bias = bv[m];
#pragma unroll
      for (int fn = 0; fn < 4; ++fn) {
        int n = n0 + wn * 64 + fn * 16 + cc;
        Vb[(size_t)m * HW_ + n] = (bf16_t)(acc[fm][fn][j] + bias);
      }
    }
  }
}

// ---------------- fused attention: QK^T + softmax(v) + PV + epilogue ----------------
// Block 128c x (2w x 64v), 4 waves (wm,wn). s-loop over k (64 steps).
// LDS: A dbuf [0,32K) | K dbuf [32K,48K) | Q [48K,64K) | P [64K,80K).
__global__ __launch_bounds__(256) void k_att(const bf16_t* __restrict__ qfT,
                                             const bf16_t* __restrict__ kfT,
                                             const bf16_t* __restrict__ Vp2,
                                             const float* __restrict__ x,
                                             const float* __restrict__ gamma,
                                             float* __restrict__ outp) {
  __shared__ char Ls[81920];
  const int lin = blockIdx.x + (blockIdx.y << 2) + (blockIdx.z << 7);
  const int rsw = (lin & 7) * 64 + (lin >> 3);   // bijective: 512 = 8*64
  const int c0 = (rsw & 3) * 128;
  const int w0 = ((rsw >> 2) & 31) * 2;
  const int b = rsw >> 7;
  const char* qb = (const char*)(qfT + (size_t)b * HW_ * CQ);
  const char* kb = (const char*)(kfT + (size_t)b * HW_ * CQ);
  const char* Vb = (const char*)(Vp2 + (size_t)b * CIN * HW_);
  const int tid = threadIdx.x, wv_ = tid >> 6, lane = tid & 63;
  const int wm = wv_ >> 1, wn = wv_ & 1;
  const int g = lane >> 4, cc = lane & 15;
  const int ws = wv_ >> 1;  // which w this wave's QK^T m-strip belongs to

  // ---- staging source pointers ----
  const char* aSb[4];             // A (Vp2) 16KB/step, XOR-swizzled source
  const char* kSb[2];             // K (kfT) 8KB/step
#pragma unroll
  for (int r = 0; r < 4; ++r) {
    int L = (r * 4 + wv_) * 64 + lane;
    int arow = L >> 3, asl = (L & 7) ^ (arow & 7);
    aSb[r] = Vb + (size_t)(c0 + arow) * 8192 + asl * 16;
  }
#pragma unroll
  for (int i = 0; i < 2; ++i) {
    int ch = wv_ * 2 + i;
    int rr = ch * 8 + (lane >> 3);
    int sl = (lane & 7) ^ (rr & 7);
    kSb[i] = kb + (size_t)rr * 128 + sl * 16;
  }

  // ---- LDS offsets (loop-invariant) ----
  int aoff[2][4], koff[2][4], boff[2][4];
#pragma unroll
  for (int k2 = 0; k2 < 2; ++k2) {
#pragma unroll
    for (int fm = 0; fm < 4; ++fm)
      aoff[k2][fm] = (wm * 64 + fm * 16 + cc) * 128 + (((k2 * 4 + g) ^ (cc & 7)) * 16);
#pragma unroll
    for (int fn = 0; fn < 4; ++fn) {
      koff[k2][fn] = 32768 + (fn * 16 + cc) * 128 + (((k2 * 4 + g) ^ (cc & 7)) * 16);
      boff[k2][fn] = 65536 + wn * 8192 + (fn * 16 + cc) * 128 + (((k2 * 4 + g) ^ (cc & 7)) * 16);
    }
  }
  // P-write addresses (8 per thread: 2 fm x 4 fn), loop-invariant
  int poff[2][4];
#pragma unroll
  for (int fm = 0; fm < 2; ++fm) {
    int h0 = (wv_ & 1) * 32 + fm * 16 + g * 4;
#pragma unroll
    for (int fn = 0; fn < 4; ++fn) {
      int v = fn * 16 + cc;
      poff[fm][fn] = 65536 + ws * 8192 + v * 128 + (((h0 >> 3) ^ (v & 7)) * 16) + (h0 & 7) * 2;
    }
  }

  // ---- prologue: stage Q (16KB), A(0), K(0) ----
#pragma unroll
  for (int i = 0; i < 4; ++i) {   // Q gather: pixels h*64 + w0 + dw
    int ch = wv_ * 4 + i;
    int rr = ch * 8 + (lane >> 3);
    int sl = (lane & 7) ^ (rr & 7);
    int pix = (rr & 63) * 64 + w0 + (rr >> 6);
    gload16(qb + (size_t)pix * 128 + sl * 16, Ls + 49152 + ch * 1024);
  }
#pragma unroll
  for (int r = 0; r < 4; ++r) gload16(aSb[r], Ls + (r * 4 + wv_) * 1024);
#pragma unroll
  for (int i = 0; i < 2; ++i) gload16(kSb[i], Ls + 32768 + (wv_ * 2 + i) * 1024);
  asm volatile("s_waitcnt vmcnt(0)" ::: "memory");
  __builtin_amdgcn_s_barrier();

  // Q-frags -> registers (m-strip rows [wv_*32, wv_*32+32))
  bf16x8 qf[2][2];
#pragma unroll
  for (int fm = 0; fm < 2; ++fm)
#pragma unroll
    for (int k2 = 0; k2 < 2; ++k2)
      qf[fm][k2] = *(const bf16x8*)(Ls + 49152 + (wv_ * 32 + fm * 16 + cc) * 128 +
                                    (((k2 * 4 + g) ^ (cc & 7)) * 16));

  f32x4 acc[4][4]{};
  for (int s = 0; s < 64; ++s) {
    const int cur = s & 1, nxt = cur ^ 1;
    // ---- stage next A/K ----
    if (s < 63) {
#pragma unroll
      for (int r = 0; r < 4; ++r)
        gload16(aSb[r] + (size_t)(s + 1) * 128, Ls + nxt * 16384 + (r * 4 + wv_) * 1024);
#pragma unroll
      for (int i = 0; i < 2; ++i)
        gload16(kSb[i] + (size_t)(s + 1) * 8192, Ls + 32768 + nxt * 8192 + (wv_ * 2 + i) * 1024);
      asm volatile("s_waitcnt vmcnt(6)" ::: "memory");
    } else {
      asm volatile("s_waitcnt vmcnt(0)" ::: "memory");
    }
    __builtin_amdgcn_s_barrier();   // staged(s) ready; P(s-1) reads done (lgkm below)

    // ---- QK^T: e[m=(ws,h)][v], m-strip per wave ----
    f32x4 eacc[2][4]{};
#pragma unroll
    for (int k2 = 0; k2 < 2; ++k2) {
      bf16x8 kf[4];
#pragma unroll
      for (int fn = 0; fn < 4; ++fn)
        kf[fn] = *(const bf16x8*)(Ls + cur * 8192 + koff[k2][fn]);
#pragma unroll
      for (int fm = 0; fm < 2; ++fm)
#pragma unroll
        for (int fn = 0; fn < 4; ++fn)
          eacc[fm][fn] = __builtin_amdgcn_mfma_f32_16x16x32_bf16(qf[fm][k2], kf[fn], eacc[fm][fn], 0, 0, 0);
    }
    // ---- softmax over v (no max-sub; sum-only butterfly over 16 cc-lanes) ----
#pragma unroll
    for (int fm = 0; fm < 2; ++fm) {
      float e[4][4], invj[4];
#pragma unroll
      for (int j = 0; j < 4; ++j) {
        float sum = 0.f;
#pragma unroll
        for (int fn = 0; fn < 4; ++fn) { e[fn][j] = __expf(eacc[fm][fn][j]); sum += e[fn][j]; }
#pragma unroll
        for (int d = 1; d < 16; d <<= 1) sum += __shfl_xor(sum, d, 64);
        invj[j] = __builtin_amdgcn_rcpf(sum);
      }
#pragma unroll
      for (int fn = 0; fn < 4; ++fn) {
        bf16x4 pk = { (bf16_t)(e[fn][0] * invj[0]), (bf16_t)(e[fn][1] * invj[1]),
                      (bf16_t)(e[fn][2] * invj[2]), (bf16_t)(e[fn][3] * invj[3]) };
        *(bf16x4*)(Ls + poff[fm][fn]) = pk;
      }
    }
    asm volatile("s_waitcnt lgkmcnt(0)" ::: "memory");
    __builtin_amdgcn_s_barrier();   // P-tile(s) visible to all waves

    // ---- PV: out += A(s) * P(s) ----
#pragma unroll
    for (int k2 = 0; k2 < 2; ++k2) {
      bf16x8 a[4], bb[4];
#pragma unroll
      for (int fm = 0; fm < 4; ++fm) a[fm] = *(const bf16x8*)(Ls + cur * 16384 + aoff[k2][fm]);
#pragma unroll
      for (int fn = 0; fn < 4; ++fn) bb[fn] = *(const bf16x8*)(Ls + boff[k2][fn]);
#pragma unroll
      for (int fm = 0; fm < 4; ++fm)
#pragma unroll
        for (int fn = 0; fn < 4; ++fn)
          acc[fm][fn] = __builtin_amdgcn_mfma_f32_16x16x32_bf16(a[fm], bb[fn], acc[fm][fn], 0, 0, 0);
    }
    asm volatile("s_waitcnt lgkmcnt(0)" ::: "memory");
    __builtin_amdgcn_s_barrier();   // PV(s) reads done before P(s+1) write / A,K overwrite
  }

  const float gmm = gamma[0];
  const float* xb = x + (size_t)b * CIN * HW_;
  float* ob = outp + (size_t)b * CIN * HW_;
  const int w = w0 + wn;
#pragma unroll
  for (int fm = 0; fm < 4; ++fm) {
#pragma unroll
    for (int jj = 0; jj < 4; ++jj) {
      int c = c0 + wm * 64 + fm * 16 + g * 4 + jj;
#pragma unroll
      for (int fn = 0; fn < 4; ++fn) {
        int n = w * 64 + fn * 16 + cc;
        size_t idx = (size_t)c * HW_ + n;
        ob[idx] = gmm * acc[fm][fn][jj] + xb[idx];
      }
    }
  }
}

extern "C" void kernel_launch(void* const* d_in, const int* in_sizes, int n_in,
                              void* d_out, int out_size, void* d_ws, size_t ws_size,
                              hipStream_t stream) {
  const float* x  = (const float*)d_in[0];
  const float* wq = (const float*)d_in[1];
  const float* bq = (const float*)d_in[2];
  const float* wk = (const float*)d_in[3];
  const float* bk = (const float*)d_in[4];
  const float* wv = (const float*)d_in[5];
  const float* bv = (const float*)d_in[6];
  const float* gamma = (const float*)d_in[7];
  float* outp = (float*)d_out;
  char* ws = (char*)d_ws;
  size_t off = 0;
  bf16_t* xT   = (bf16_t*)(ws + off); off += (size_t)4 * HW_ * CIN * 2;   // 16 MB
  bf16_t* Wcat = (bf16_t*)(ws + off); off += (size_t)640 * CIN * 2;       // 640 KB
  bf16_t* qfT  = (bf16_t*)(ws + off); off += (size_t)4 * HW_ * CQ * 2;    // 2 MB
  bf16_t* kfT  = (bf16_t*)(ws + off); off += (size_t)4 * HW_ * CQ * 2;    // 2 MB
  bf16_t* Vp2  = (bf16_t*)(ws + off);                                     // 16 MB

  k_wcat<<<dim3(320), dim3(256), 0, stream>>>(wq, wk, wv, Wcat);
  k_prep<<<dim3(64, 8, 4), dim3(256), 0, stream>>>(x, xT);
  k_projqk<<<dim3(32, 1, 4), dim3(256), 0, stream>>>(Wcat, xT, bq, bk, qfT, kfT);
  k_projv<<<dim3(32, 4, 4), dim3(256), 0, stream>>>(Wcat, xT, bv, Vp2);
  k_att<<<dim3(4, 32, 4), dim3(256), 0, stream>>>(qfT, kfT, Vp2, x, gamma, outp);
}

// Round 15
// 170.910 us; speedup vs baseline: 1.3135x; 1.3135x over previous
//
#include <hip/hip_runtime.h>
#include <hip/hip_bf16.h>

// CrissCrossAttention: B=4, C=512, H=W=64. v9 = v7 pipeline with 256c k_out tile.
//   k_wcat/k_prep/k_projqk/k_projv/k_energy: unchanged from v7 (validated).
//   k_out: block 256c x (2w x 64v), 8 waves (4 wm x 2 wn), LDS 96KB
//          (A 2x32KB dbuf | B 2x16KB dbuf), vmcnt(6), XCD swizzle pairs the
//          2 c-blocks of each w-panel on one XCD. Staged bytes/CU/step 64->48KB.

typedef __bf16 bf16_t;
typedef __bf16 bf16x8 __attribute__((ext_vector_type(8)));
typedef __bf16 bf16x4 __attribute__((ext_vector_type(4)));
typedef float f32x4 __attribute__((ext_vector_type(4)));

#define HW_ 4096
#define CIN 512
#define CQ 64

__device__ __forceinline__ void gload16(const void* g, void* l) {
  __builtin_amdgcn_global_load_lds((const __attribute__((address_space(1))) void*)g,
                                   (__attribute__((address_space(3))) void*)l, 16, 0, 0);
}

// ---------------- weights pack ----------------
__global__ __launch_bounds__(256) void k_wcat(const float* __restrict__ wq,
                                              const float* __restrict__ wk,
                                              const float* __restrict__ wv,
                                              bf16_t* __restrict__ Wcat) {
  int idx = (blockIdx.x * 256 + threadIdx.x) * 4;
  int row = idx >> 9, c = idx & 511;
  const float* src;
  if (row < 64)       src = wq + row * 512 + c;
  else if (row < 128) src = wk + (row - 64) * 512 + c;
  else                src = wv + (row - 128) * 512 + c;
  float4 v = *(const float4*)src;
  bf16x4 o = { (bf16_t)v.x, (bf16_t)v.y, (bf16_t)v.z, (bf16_t)v.w };
  *(bf16x4*)&Wcat[idx] = o;
}

// ---------------- x transpose + bf16 ----------------
__global__ __launch_bounds__(256) void k_prep(const float* __restrict__ x, bf16_t* __restrict__ xT) {
  __shared__ float tile[64][65];
  const int b = blockIdx.z;
  const int p0 = blockIdx.x * 64, c0 = blockIdx.y * 64;
  const float* xb = x + (size_t)b * CIN * HW_;
  bf16_t* xTb = xT + (size_t)b * HW_ * CIN;
  const int tid = threadIdx.x;
  const int r = tid >> 4, q = tid & 15;
#pragma unroll
  for (int i = 0; i < 4; ++i) {
    int lr = r + 16 * i;
    float4 v = *(const float4*)&xb[(size_t)(c0 + lr) * HW_ + p0 + q * 4];
    tile[lr][q * 4 + 0] = v.x; tile[lr][q * 4 + 1] = v.y;
    tile[lr][q * 4 + 2] = v.z; tile[lr][q * 4 + 3] = v.w;
  }
  __syncthreads();
#pragma unroll
  for (int i = 0; i < 4; ++i) {
    int pr = r + 16 * i;
    bf16x4 o;
    o[0] = (bf16_t)tile[q * 4 + 0][pr];
    o[1] = (bf16_t)tile[q * 4 + 1][pr];
    o[2] = (bf16_t)tile[q * 4 + 2][pr];
    o[3] = (bf16_t)tile[q * 4 + 3][pr];
    *(bf16x4*)&xTb[(size_t)(p0 + pr) * CIN + c0 + q * 4] = o;
  }
}

// ---------------- q/k projection GEMM (Wcat rows 0..127) ----------------
__global__ __launch_bounds__(256) void k_projqk(const bf16_t* __restrict__ Wcat,
                                                const bf16_t* __restrict__ xT,
                                                const float* __restrict__ bq,
                                                const float* __restrict__ bk,
                                                bf16_t* __restrict__ qfT,
                                                bf16_t* __restrict__ kfT) {
  __shared__ bf16_t As[128][64];
  __shared__ bf16_t Bs[128][64];
  const int b = blockIdx.z;
  const int n0 = blockIdx.x * 128;
  const char* Wb = (const char*)Wcat;
  const char* Xb = (const char*)(xT + (size_t)b * HW_ * CIN);
  const int tid = threadIdx.x, wv_ = tid >> 6, lane = tid & 63;
  const int wm = wv_ >> 1, wn = wv_ & 1;
  const int g = lane >> 4, cc = lane & 15;
  f32x4 acc[4][4]{};
  for (int ks = 0; ks < 512; ks += 64) {
    if (ks) __syncthreads();
#pragma unroll
    for (int i = 0; i < 4; ++i) {
      int ch = wv_ * 4 + i;
      int rr = ch * 8 + (lane >> 3);
      int sl = (lane & 7) ^ (rr & 7);
      gload16(Wb + (size_t)rr * 1024 + ks * 2 + sl * 16, (char*)As + ch * 1024);
      gload16(Xb + (size_t)(n0 + rr) * 1024 + ks * 2 + sl * 16, (char*)Bs + ch * 1024);
    }
    __syncthreads();
#pragma unroll
    for (int k2 = 0; k2 < 2; ++k2) {
      bf16x8 a[4], bb[4];
#pragma unroll
      for (int f = 0; f < 4; ++f)
        a[f] = *(const bf16x8*)((char*)As + (wm * 64 + f * 16 + cc) * 128 + (((k2 * 4 + g) ^ (cc & 7)) * 16));
#pragma unroll
      for (int f = 0; f < 4; ++f)
        bb[f] = *(const bf16x8*)((char*)Bs + (wn * 64 + f * 16 + cc) * 128 + (((k2 * 4 + g) ^ (cc & 7)) * 16));
#pragma unroll
      for (int fm = 0; fm < 4; ++fm)
#pragma unroll
        for (int fn = 0; fn < 4; ++fn)
          acc[fm][fn] = __builtin_amdgcn_mfma_f32_16x16x32_bf16(a[fm], bb[fn], acc[fm][fn], 0, 0, 0);
    }
  }
  bf16_t* qb = qfT + (size_t)b * HW_ * CQ;
  bf16_t* kb = kfT + (size_t)b * HW_ * CQ;
#pragma unroll
  for (int fm = 0; fm < 4; ++fm) {
#pragma unroll
    for (int j = 0; j < 4; ++j) {
      int m = wm * 64 + fm * 16 + g * 4 + j;
      float bias = (m < 64) ? bq[m] : bk[m - 64];
#pragma unroll
      for (int fn = 0; fn < 4; ++fn) {
        int n = n0 + wn * 64 + fn * 16 + cc;
        float val = acc[fm][fn][j] + bias;
        if (m < 64) qb[(size_t)n * CQ + m] = (bf16_t)val;
        else        kb[(size_t)n * CQ + (m - 64)] = (bf16_t)val;
      }
    }
  }
}

// ---------------- V projection GEMM (Wcat rows 128..639, permuted pixels) ----------------
__global__ __launch_bounds__(256) void k_projv(const bf16_t* __restrict__ Wcat,
                                               const bf16_t* __restrict__ xT,
                                               const float* __restrict__ bv,
                                               bf16_t* __restrict__ Vp2) {
  __shared__ bf16_t As[128][64];
  __shared__ bf16_t Bs[128][64];
  const int b = blockIdx.z;
  const int n0 = blockIdx.x * 128, m0 = blockIdx.y * 128;
  const char* Wb = (const char*)Wcat;
  const char* Xb = (const char*)(xT + (size_t)b * HW_ * CIN);
  const int tid = threadIdx.x, wv_ = tid >> 6, lane = tid & 63;
  const int wm = wv_ >> 1, wn = wv_ & 1;
  const int g = lane >> 4, cc = lane & 15;
  f32x4 acc[4][4]{};
  for (int ks = 0; ks < 512; ks += 64) {
    if (ks) __syncthreads();
#pragma unroll
    for (int i = 0; i < 4; ++i) {
      int ch = wv_ * 4 + i;
      int rr = ch * 8 + (lane >> 3);
      int sl = (lane & 7) ^ (rr & 7);
      int pix = (rr & 63) * 64 + (blockIdx.x * 2) + (rr >> 6);  // perm(n0+rr)
      gload16(Wb + (size_t)(128 + m0 + rr) * 1024 + ks * 2 + sl * 16, (char*)As + ch * 1024);
      gload16(Xb + (size_t)pix * 1024 + ks * 2 + sl * 16, (char*)Bs + ch * 1024);
    }
    __syncthreads();
#pragma unroll
    for (int k2 = 0; k2 < 2; ++k2) {
      bf16x8 a[4], bb[4];
#pragma unroll
      for (int f = 0; f < 4; ++f)
        a[f] = *(const bf16x8*)((char*)As + (wm * 64 + f * 16 + cc) * 128 + (((k2 * 4 + g) ^ (cc & 7)) * 16));
#pragma unroll
      for (int f = 0; f < 4; ++f)
        bb[f] = *(const bf16x8*)((char*)Bs + (wn * 64 + f * 16 + cc) * 128 + (((k2 * 4 + g) ^ (cc & 7)) * 16));
#pragma unroll
      for (int fm = 0; fm < 4; ++fm)
#pragma unroll
        for (int fn = 0; fn < 4; ++fn)
          acc[fm][fn] = __builtin_amdgcn_mfma_f32_16x16x32_bf16(a[fm], bb[fn], acc[fm][fn], 0, 0, 0);
    }
  }
  bf16_t* Vb = Vp2 + (size_t)b * CIN * HW_;
#pragma unroll
  for (int fm = 0; fm < 4; ++fm) {
#pragma unroll
    for (int j = 0; j < 4; ++j) {
      int m = m0 + wm * 64 + fm * 16 + g * 4 + j;
      float bias = bv[m];
#pragma unroll
      for (int fn = 0; fn < 4; ++fn) {
        int n = n0 + wn * 64 + fn * 16 + cc;
        Vb[(size_t)m * HW_ + n] = (bf16_t)(acc[fm][fn][j] + bias);
      }
    }
  }
}

// ---------------- energy + softmax(v) -> Pt[b][w][k][v][h] ----------------
__global__ __launch_bounds__(256) void k_energy(const bf16_t* __restrict__ qfT,
                                                const bf16_t* __restrict__ kfT,
                                                bf16_t* __restrict__ Pt, int zbase) {
  __shared__ bf16_t As[128][64];
  __shared__ bf16_t Bs[64][64];
  const int b = zbase + blockIdx.z;
  const int w0 = blockIdx.x * 2, ky = blockIdx.y;
  const char* qb = (const char*)(qfT + (size_t)b * HW_ * CQ);
  const char* kb = (const char*)(kfT + (size_t)b * HW_ * CQ);
  bf16_t* Ptb = Pt + (size_t)blockIdx.z * 16777216;
  const int tid = threadIdx.x, wv_ = tid >> 6, lane = tid & 63;
  const int g = lane >> 4, cc = lane & 15;
  f32x4 acc[2][4]{};
#pragma unroll
  for (int i = 0; i < 4; ++i) {
    int ch = wv_ * 4 + i;
    int rr = ch * 8 + (lane >> 3);
    int sl = (lane & 7) ^ (rr & 7);
    int pix = (rr & 63) * 64 + w0 + (rr >> 6);
    gload16(qb + (size_t)pix * 128 + sl * 16, (char*)As + ch * 1024);
  }
#pragma unroll
  for (int i = 0; i < 2; ++i) {
    int ch = wv_ * 2 + i;
    int rr = ch * 8 + (lane >> 3);
    int sl = (lane & 7) ^ (rr & 7);
    gload16(kb + (size_t)(ky * 64 + rr) * 128 + sl * 16, (char*)Bs + ch * 1024);
  }
  __syncthreads();
#pragma unroll
  for (int k2 = 0; k2 < 2; ++k2) {
    bf16x8 a[2], bb[4];
#pragma unroll
    for (int f = 0; f < 2; ++f)
      a[f] = *(const bf16x8*)((char*)As + (wv_ * 32 + f * 16 + cc) * 128 + (((k2 * 4 + g) ^ (cc & 7)) * 16));
#pragma unroll
    for (int f = 0; f < 4; ++f)
      bb[f] = *(const bf16x8*)((char*)Bs + (f * 16 + cc) * 128 + (((k2 * 4 + g) ^ (cc & 7)) * 16));
#pragma unroll
    for (int fm = 0; fm < 2; ++fm)
#pragma unroll
      for (int fn = 0; fn < 4; ++fn)
        acc[fm][fn] = __builtin_amdgcn_mfma_f32_16x16x32_bf16(a[fm], bb[fn], acc[fm][fn], 0, 0, 0);
  }
  const int w = w0 + (wv_ >> 1);
#pragma unroll
  for (int fm = 0; fm < 2; ++fm) {
    float e[4][4], invj[4];
#pragma unroll
    for (int j = 0; j < 4; ++j) {
      float mx = fmaxf(fmaxf(acc[fm][0][j], acc[fm][1][j]), fmaxf(acc[fm][2][j], acc[fm][3][j]));
#pragma unroll
      for (int d = 1; d < 16; d <<= 1) mx = fmaxf(mx, __shfl_xor(mx, d, 64));
      float s = 0.f;
#pragma unroll
      for (int fn = 0; fn < 4; ++fn) { e[fn][j] = __expf(acc[fm][fn][j] - mx); s += e[fn][j]; }
#pragma unroll
      for (int d = 1; d < 16; d <<= 1) s += __shfl_xor(s, d, 64);
      invj[j] = __builtin_amdgcn_rcpf(s);
    }
    int h0 = (wv_ & 1) * 32 + fm * 16 + g * 4;
#pragma unroll
    for (int fn = 0; fn < 4; ++fn) {
      int v = fn * 16 + cc;
      bf16x4 pk = { (bf16_t)(e[fn][0] * invj[0]), (bf16_t)(e[fn][1] * invj[1]),
                    (bf16_t)(e[fn][2] * invj[2]), (bf16_t)(e[fn][3] * invj[3]) };
      *(bf16x4*)&Ptb[(((size_t)w * 64 + ky) * 64 + v) * 64 + h0] = pk;
    }
  }
}

// ---------------- out GEMM v9 + epilogue ----------------
// Block 256c x (2w x 64v), 8 waves (wm=wv>>1 in 0..3, wn=wv&1). K-step s = k.
// LDS 96KB: A 2x32KB dbuf [0,64K) | B 2x16KB dbuf [64K,96K). vmcnt(6).
__global__ __launch_bounds__(512) void k_out(const bf16_t* __restrict__ Vp2,
                                             const bf16_t* __restrict__ Pt,
                                             const float* __restrict__ x,
                                             const float* __restrict__ gamma,
                                             float* __restrict__ outp, int zbase) {
  __shared__ char Ls[98304];
  const int lin = blockIdx.x + (blockIdx.y << 1) + (blockIdx.z << 6);
  const int nwg8 = (gridDim.z == 4) ? 32 : 8;
  const int rsw = (lin & 7) * nwg8 + (lin >> 3);
  const int c0 = (rsw & 1) * 256;
  const int w0 = ((rsw >> 1) & 31) * 2;
  const int bz = (gridDim.z == 4) ? (rsw >> 6) : 0;
  const int b = zbase + bz;
  const char* Vb = (const char*)(Vp2 + (size_t)b * CIN * HW_);
  const char* Pb = (const char*)(Pt + (size_t)bz * 16777216);
  const int tid = threadIdx.x, wv_ = tid >> 6, lane = tid & 63;
  const int wm = wv_ >> 1, wn = wv_ & 1;
  const int g = lane >> 4, cc = lane & 15;

  const char* aSb[4]; const char* bSb[2];
#pragma unroll
  for (int r = 0; r < 4; ++r) {
    int L = (r * 8 + wv_) * 64 + lane;              // 0..2047 (A: 32KB)
    int arow = L >> 3, asl = (L & 7) ^ (arow & 7);
    aSb[r] = Vb + (size_t)(c0 + arow) * 8192 + asl * 16;
  }
#pragma unroll
  for (int r = 0; r < 2; ++r) {
    int L = (r * 8 + wv_) * 64 + lane;              // 0..1023 (B: 16KB)
    int ws = L >> 9, e = L & 511, v = e >> 3, bsl = (e & 7) ^ (v & 7);
    bSb[r] = Pb + (size_t)(w0 + ws) * 524288 + v * 128 + bsl * 16;
  }
  int aoff[2][4], boff[2][4];
#pragma unroll
  for (int k2 = 0; k2 < 2; ++k2) {
#pragma unroll
    for (int fm = 0; fm < 4; ++fm)
      aoff[k2][fm] = (wm * 64 + fm * 16 + cc) * 128 + (((k2 * 4 + g) ^ (cc & 7)) * 16);
#pragma unroll
    for (int fn = 0; fn < 4; ++fn)
      boff[k2][fn] = 65536 + wn * 8192 + (fn * 16 + cc) * 128 + (((k2 * 4 + g) ^ (cc & 7)) * 16);
  }

  f32x4 acc[4][4]{};
  // prologue: stage s=0 into buf0
#pragma unroll
  for (int r = 0; r < 4; ++r) gload16(aSb[r], Ls + (r * 8 + wv_) * 1024);
#pragma unroll
  for (int r = 0; r < 2; ++r) gload16(bSb[r], Ls + 65536 + (r * 8 + wv_) * 1024);

  for (int s = 0; s < 64; ++s) {
    const int cur = s & 1;
    if (s < 63) {
      const int nxt = cur ^ 1;
#pragma unroll
      for (int r = 0; r < 4; ++r)
        gload16(aSb[r] + (size_t)(s + 1) * 128, Ls + nxt * 32768 + (r * 8 + wv_) * 1024);
#pragma unroll
      for (int r = 0; r < 2; ++r)
        gload16(bSb[r] + (size_t)(s + 1) * 8192, Ls + 65536 + nxt * 16384 + (r * 8 + wv_) * 1024);
      asm volatile("s_waitcnt vmcnt(6)" ::: "memory");
    } else {
      asm volatile("s_waitcnt vmcnt(0)" ::: "memory");
    }
    __builtin_amdgcn_s_barrier();
#pragma unroll
    for (int k2 = 0; k2 < 2; ++k2) {
      bf16x8 a[4], bb[4];
#pragma unroll
      for (int fm = 0; fm < 4; ++fm) a[fm] = *(const bf16x8*)(Ls + cur * 32768 + aoff[k2][fm]);
#pragma unroll
      for (int fn = 0; fn < 4; ++fn) bb[fn] = *(const bf16x8*)(Ls + cur * 16384 + boff[k2][fn]);
#pragma unroll
      for (int fm = 0; fm < 4; ++fm)
#pragma unroll
        for (int fn = 0; fn < 4; ++fn)
          acc[fm][fn] = __builtin_amdgcn_mfma_f32_16x16x32_bf16(a[fm], bb[fn], acc[fm][fn], 0, 0, 0);
    }
    asm volatile("s_waitcnt lgkmcnt(0)" ::: "memory");
    __builtin_amdgcn_s_barrier();
  }
  const float gmm = gamma[0];
  const float* xb = x + (size_t)b * CIN * HW_;
  float* ob = outp + (size_t)b * CIN * HW_;
  const int w = w0 + wn;
#pragma unroll
  for (int fm = 0; fm < 4; ++fm) {
#pragma unroll
    for (int jj = 0; jj < 4; ++jj) {
      int c = c0 + wm * 64 + fm * 16 + g * 4 + jj;
#pragma unroll
      for (int fn = 0; fn < 4; ++fn) {
        int n = w * 64 + fn * 16 + cc;
        size_t idx = (size_t)c * HW_ + n;
        ob[idx] = gmm * acc[fm][fn][jj] + xb[idx];
      }
    }
  }
}

extern "C" void kernel_launch(void* const* d_in, const int* in_sizes, int n_in,
                              void* d_out, int out_size, void* d_ws, size_t ws_size,
                              hipStream_t stream) {
  const float* x  = (const float*)d_in[0];
  const float* wq = (const float*)d_in[1];
  const float* bq = (const float*)d_in[2];
  const float* wk = (const float*)d_in[3];
  const float* bk = (const float*)d_in[4];
  const float* wv = (const float*)d_in[5];
  const float* bv = (const float*)d_in[6];
  const float* gamma = (const float*)d_in[7];
  float* outp = (float*)d_out;
  char* ws = (char*)d_ws;
  size_t off = 0;
  bf16_t* xT   = (bf16_t*)(ws + off); off += (size_t)4 * HW_ * CIN * 2;   // 16 MB
  bf16_t* Wcat = (bf16_t*)(ws + off); off += (size_t)640 * CIN * 2;       // 640 KB
  bf16_t* qfT  = (bf16_t*)(ws + off); off += (size_t)4 * HW_ * CQ * 2;    // 2 MB
  bf16_t* kfT  = (bf16_t*)(ws + off); off += (size_t)4 * HW_ * CQ * 2;    // 2 MB
  bf16_t* Vp2  = (bf16_t*)(ws + off); off += (size_t)4 * CIN * HW_ * 2;   // 16 MB
  bf16_t* Pt   = (bf16_t*)(ws + off);
  const size_t pbytes = (size_t)HW_ * HW_ * 2;                            // 32 MB / batch
  const bool full = (ws_size >= off + 4 * pbytes);

  k_wcat<<<dim3(320), dim3(256), 0, stream>>>(wq, wk, wv, Wcat);
  k_prep<<<dim3(64, 8, 4), dim3(256), 0, stream>>>(x, xT);
  k_projqk<<<dim3(32, 1, 4), dim3(256), 0, stream>>>(Wcat, xT, bq, bk, qfT, kfT);
  k_projv<<<dim3(32, 4, 4), dim3(256), 0, stream>>>(Wcat, xT, bv, Vp2);
  if (full) {
    k_energy<<<dim3(32, 64, 4), dim3(256), 0, stream>>>(qfT, kfT, Pt, 0);
    k_out<<<dim3(2, 32, 4), dim3(512), 0, stream>>>(Vp2, Pt, x, gamma, outp, 0);
  } else {
    for (int b = 0; b < 4; ++b) {
      k_energy<<<dim3(32, 64, 1), dim3(256), 0, stream>>>(qfT, kfT, Pt, b);
      k_out<<<dim3(2, 32, 1), dim3(512), 0, stream>>>(Vp2, Pt, x, gamma, outp, b);
    }
  }
}